// Round 6
// baseline (1040.139 us; speedup 1.0000x reference)
//
#include <hip/hip_runtime.h>
#include <hip/hip_bf16.h>
#include <math.h>

using bf16 = __hip_bfloat16;
typedef __attribute__((ext_vector_type(8)))  __bf16 bf16x8;
typedef __attribute__((ext_vector_type(4)))  float  f32x4;
typedef __attribute__((ext_vector_type(16))) float  f32x16;

__device__ __forceinline__ float b2f(bf16 x){ return __bfloat162float(x); }
__device__ __forceinline__ bf16  f2b(float x){ return __float2bfloat16(x); }
__device__ __forceinline__ float ldf(const float* p, size_t i){ return p[i]; }
__device__ __forceinline__ float ldf(const bf16*  p, size_t i){ return b2f(p[i]); }
__device__ __forceinline__ void stf(float* p, size_t i, float v){ p[i] = v; }
__device__ __forceinline__ void stf(bf16*  p, size_t i, float v){ p[i] = f2b(v); }

// fast gelu: tanh form, |err| ~1e-3 (threshold margin is 1.7x)
__device__ __forceinline__ float gelu_f(float v){
  float u = v*(0.7978845608f + 0.0356774081f*v*v);
  float e = __expf(2.f*u);
  float t = 1.f - 2.f/(e+1.f);
  return 0.5f*v*(1.f+t);
}

// async 16B global->LDS (wave-uniform LDS base + lane*16)
typedef const __attribute__((address_space(1))) unsigned int* gas_u32p;
typedef __attribute__((address_space(3))) unsigned int* las_u32p;
__device__ __forceinline__ void gl_lds16(const bf16* g, bf16* l){
  __builtin_amdgcn_global_load_lds((gas_u32p)(const void*)g, (las_u32p)(void*)l, 16, 0, 0);
}

#define NHEAD 12
#define HDIM  64
#define HID   768
#define SEQ   512
#define BATCH 32
#define ROWS  (BATCH*SEQ)   // 16384
#define QKVW  2304          // packed qkv row width
#define QCH   128           // q-chunk rows for attention
#define NCHUNK (SEQ/QCH)    // 4
#define FT    128           // flash key tile

// ---------------------------------------------------------------------------
// MFMA GEMM (32x32x16): C[M,N] = A[M,K] * Bt[N,K]^T (+bias +epilogue).
// 128x128 block, 4 waves as 2x2 of 64x64, each wave 2x2 tiles of 32x32.
// Staging via global_load_lds(16B) + XOR bank swizzle (same scheme that
// zeroed SQ_LDS_BANK_CONFLICT in round 3).
// A/B frag: row/col = lane&31, k = (lane>>5)*8 + reg (extends verified
// 16x16x32 mapping). C/D: col=lane&31, row=(reg&3)+8*(reg>>2)+4*(lane>>5)
// (m74/m101-verified). EPI: 0=bias, 1=bias+gelu, 2=bias+residual.
// ---------------------------------------------------------------------------
template<int EPI,typename TR>
__global__ __launch_bounds__(256)
void gemm_bt(const bf16* __restrict__ A, int lda,
             const bf16* __restrict__ Bt, int ldb,
             bf16* __restrict__ C, int ldc,
             int K,
             const float* __restrict__ bias,
             const TR* __restrict__ res, int ldres)
{
  constexpr int BM = 128, BN = 128, BK = 32;
  const int m0 = blockIdx.y*BM, n0 = blockIdx.x*BN;
  __shared__ __align__(16) bf16 As[BM*BK];
  __shared__ __align__(16) bf16 Bs[BN*BK];

  const int tid  = threadIdx.x;
  const int wave = tid>>6, lane = tid&63;
  const int rl = lane&31, g = lane>>5;
  const int wr = wave>>1, wc = wave&1;
  const int sw = (rl>>1)&3;               // read-side swizzle term

  f32x16 acc[2][2] = {};

  for (int k0=0;k0<K;k0+=BK){
    #pragma unroll
    for (int c0=0;c0<512;c0+=256){
      int c = c0 + tid;
      int row = c>>2;
      int kc  = (c&3) ^ ((c>>3)&3);
      gl_lds16(A + (size_t)(m0+row)*lda + k0 + kc*8,
               As + ((size_t)c0 + (size_t)wave*64)*8);
    }
    #pragma unroll
    for (int c0=0;c0<512;c0+=256){
      int c = c0 + tid;
      int row = c>>2;
      int kc  = (c&3) ^ ((c>>3)&3);
      gl_lds16(Bt + (size_t)(n0+row)*ldb + k0 + kc*8,
               Bs + ((size_t)c0 + (size_t)wave*64)*8);
    }
    __syncthreads();
    #pragma unroll
    for (int ks=0; ks<2; ks++){
      bf16x8 af[2], bfv[2];
      int j = ks*2 + g;
      #pragma unroll
      for (int ti=0;ti<2;ti++)
        af[ti] = *(const bf16x8*)(As + (wr*64 + ti*32 + rl)*BK + ((j^sw)*8));
      #pragma unroll
      for (int tj=0;tj<2;tj++)
        bfv[tj] = *(const bf16x8*)(Bs + (wc*64 + tj*32 + rl)*BK + ((j^sw)*8));
      #pragma unroll
      for (int ti=0;ti<2;ti++)
        #pragma unroll
        for (int tj=0;tj<2;tj++)
          acc[ti][tj] = __builtin_amdgcn_mfma_f32_32x32x16_bf16(af[ti], bfv[tj], acc[ti][tj], 0,0,0);
    }
    __syncthreads();
  }

  #pragma unroll
  for (int ti=0;ti<2;ti++){
    #pragma unroll
    for (int tj=0;tj<2;tj++){
      #pragma unroll
      for (int reg=0;reg<16;reg++){
        int rowL = (reg&3) + 8*(reg>>2) + 4*g;
        int mm = m0 + wr*64 + ti*32 + rowL;
        int nn = n0 + wc*64 + tj*32 + rl;
        float v = acc[ti][tj][reg];
        if (bias) v += bias[nn];
        if (EPI==1) v = gelu_f(v);
        if (EPI==2) v += ldf(res, (size_t)mm*ldres + nn);
        C[(size_t)mm*ldc + nn] = f2b(v);
      }
    }
  }
}

// ---------------------------------------------------------------------------
// Fused flash attention (16x16x32, validated round 5). One block = one
// (b,h) x 128-row q-chunk. LDS 48.5 KB; P aliases Ks.
// ---------------------------------------------------------------------------
__global__ __launch_bounds__(256)
void flash_attn(const bf16* __restrict__ qkv, const bf16* __restrict__ vtb,
                const float* __restrict__ mask, bf16* __restrict__ ctx)
{
  const int qc = blockIdx.x;
  const int z  = blockIdx.y;
  const int b  = z / NHEAD, h = z - b*NHEAD;
  const int q0 = qc*QCH;

  __shared__ __align__(16) bf16 Qs[QCH*64];
  __shared__ __align__(16) bf16 Ks[FT*64];
  __shared__ __align__(16) bf16 Vts[64*FT];
  __shared__ float smask[FT];
  bf16* Ps = Ks;

  const int tid = threadIdx.x;
  const int wave = tid>>6, lane = tid&63;
  const int r = lane&15, qd = lane>>4;
  const int wr = wave;

  const bf16* Qg = qkv + ((size_t)(b*SEQ + q0))*QKVW + h*HDIM;
  const bf16* Kg = qkv + ((size_t)b*SEQ)*QKVW + 768 + h*HDIM;
  const bf16* Vg = vtb + (size_t)z*HDIM*SEQ;

  for (int c0=0;c0<1024;c0+=256){
    int c = c0+tid, row = c>>3, pos = c&7;
    gl_lds16(Qg + (size_t)row*QKVW + ((pos^(row&7))*8),
             Qs + (size_t)(c0 + wave*64)*8);
  }

  f32x4 accO[2][4] = {};
  float mrun[2][4], lrun[2][4];
  #pragma unroll
  for (int a=0;a<2;a++)
    #pragma unroll
    for (int i2=0;i2<4;i2++){ mrun[a][i2]=-1e30f; lrun[a][i2]=0.f; }

  for (int k0=0; k0<SEQ; k0+=FT){
    __syncthreads();
    for (int c0=0;c0<1024;c0+=256){
      int c = c0+tid, row = c>>3, pos = c&7;
      gl_lds16(Kg + (size_t)(k0+row)*QKVW + ((pos^(row&7))*8),
               Ks + (size_t)(c0 + wave*64)*8);
    }
    for (int c0=0;c0<1024;c0+=256){
      int c = c0+tid, row = c>>4, pos = c&15;
      gl_lds16(Vg + (size_t)row*SEQ + k0 + ((pos^(row&7))*8),
               Vts + (size_t)(c0 + wave*64)*8);
    }
    if (tid < FT) smask[tid] = mask[(size_t)b*SEQ + k0 + tid];
    __syncthreads();

    f32x4 accS[2][8] = {};
    #pragma unroll
    for (int ks=0; ks<2; ks++){
      bf16x8 af[2], bfv[8];
      #pragma unroll
      for (int mi=0;mi<2;mi++){
        int row = wr*32 + mi*16 + r;
        int jr = ks*4 + qd;
        af[mi] = *(const bf16x8*)(Qs + row*64 + ((jr^(row&7))*8));
      }
      #pragma unroll
      for (int ni=0;ni<8;ni++){
        int row = ni*16 + r;
        int jr = ks*4 + qd;
        bfv[ni] = *(const bf16x8*)(Ks + row*64 + ((jr^(row&7))*8));
      }
      #pragma unroll
      for (int mi=0;mi<2;mi++)
        #pragma unroll
        for (int ni=0;ni<8;ni++)
          accS[mi][ni] = __builtin_amdgcn_mfma_f32_16x16x32_bf16(af[mi], bfv[ni], accS[mi][ni], 0,0,0);
    }

    #pragma unroll
    for (int mi=0;mi<2;mi++){
      #pragma unroll
      for (int i=0;i<4;i++){
        float mx = -1e30f;
        #pragma unroll
        for (int ni=0;ni<8;ni++){
          float v = accS[mi][ni][i]*0.125f + smask[ni*16+r];
          accS[mi][ni][i] = v;
          mx = fmaxf(mx, v);
        }
        #pragma unroll
        for (int off=1; off<16; off<<=1) mx = fmaxf(mx, __shfl_xor(mx, off));
        float mnew = fmaxf(mrun[mi][i], mx);
        float alpha = __expf(mrun[mi][i] - mnew);
        mrun[mi][i] = mnew;
        float ssum = 0.f;
        #pragma unroll
        for (int ni=0;ni<8;ni++){
          float p = __expf(accS[mi][ni][i] - mnew);
          accS[mi][ni][i] = p;
          ssum += p;
        }
        #pragma unroll
        for (int off=1; off<16; off<<=1) ssum += __shfl_xor(ssum, off);
        lrun[mi][i] = lrun[mi][i]*alpha + ssum;
        #pragma unroll
        for (int ni=0;ni<4;ni++) accO[mi][ni][i] *= alpha;
      }
    }

    #pragma unroll
    for (int half=0; half<2; half++){
      __syncthreads();
      #pragma unroll
      for (int mi=0;mi<2;mi++){
        #pragma unroll
        for (int i=0;i<4;i++){
          int row = wr*32 + mi*16 + qd*4 + i;
          #pragma unroll
          for (int nj=0;nj<4;nj++){
            int colL = nj*16 + r;
            int chunk = colL>>3;
            Ps[row*64 + ((chunk^(row&7))*8) + (colL&7)] = f2b(accS[mi][half*4+nj][i]);
          }
        }
      }
      __syncthreads();
      #pragma unroll
      for (int ks=0; ks<2; ks++){
        bf16x8 af[2], bfv[4];
        #pragma unroll
        for (int mi=0;mi<2;mi++){
          int row = wr*32 + mi*16 + r;
          int jr = ks*4 + qd;
          af[mi] = *(const bf16x8*)(Ps + row*64 + ((jr^(row&7))*8));
        }
        #pragma unroll
        for (int ni=0;ni<4;ni++){
          int row = ni*16 + r;
          int jrv = half*8 + ks*4 + qd;
          bfv[ni] = *(const bf16x8*)(Vts + row*FT + ((jrv^(row&7))*8));
        }
        #pragma unroll
        for (int mi=0;mi<2;mi++)
          #pragma unroll
          for (int ni=0;ni<4;ni++)
            accO[mi][ni] = __builtin_amdgcn_mfma_f32_16x16x32_bf16(af[mi], bfv[ni], accO[mi][ni], 0,0,0);
      }
    }
  }

  bf16* Cg = ctx + ((size_t)(b*SEQ + q0))*HID + h*HDIM;
  #pragma unroll
  for (int mi=0;mi<2;mi++)
    #pragma unroll
    for (int i=0;i<4;i++){
      int row = wr*32 + mi*16 + qd*4 + i;
      float invl = 1.0f/lrun[mi][i];
      #pragma unroll
      for (int ni=0;ni<4;ni++)
        Cg[(size_t)row*HID + ni*16 + r] = f2b(accO[mi][ni][i]*invl);
    }
}

// ---------------------------------------------------------------------------
// Fused prep: all weight transposes + X cast + bias concat in ONE launch.
// grid (24,24,13), block (32,8).
// ---------------------------------------------------------------------------
__global__ void prep_all(const float* __restrict__ w0, const float* __restrict__ w1,
                         const float* __restrict__ w2, const float* __restrict__ w3,
                         const float* __restrict__ Wi, const float* __restrict__ Wo2,
                         const float* __restrict__ X,
                         const float* __restrict__ bq, const float* __restrict__ bk,
                         const float* __restrict__ bv,
                         bf16* __restrict__ wt4, bf16* __restrict__ wti,
                         bf16* __restrict__ wto2, bf16* __restrict__ xb,
                         float* __restrict__ bqkv)
{
  const int z = blockIdx.z;
  int tx = threadIdx.x, ty = threadIdx.y;
  __shared__ float tile[32][33];

  if (z < 4){          // 768x768 -> transpose
    const float* in = z==0?w0 : z==1?w1 : z==2?w2 : w3;
    bf16* o = wt4 + (size_t)z*768*768;
    int bc = blockIdx.x*32, br = blockIdx.y*32;
    #pragma unroll
    for (int i=ty;i<32;i+=8) tile[i][tx] = in[(size_t)(br+i)*768 + bc+tx];
    __syncthreads();
    #pragma unroll
    for (int i=ty;i<32;i+=8) o[(size_t)(bc+i)*768 + br+tx] = f2b(tile[tx][i]);
  } else if (z < 8){   // Wi [768][3072] -> wti [3072][768]
    int bc = (blockIdx.x + (z-4)*24)*32, br = blockIdx.y*32;
    #pragma unroll
    for (int i=ty;i<32;i+=8) tile[i][tx] = Wi[(size_t)(br+i)*3072 + bc+tx];
    __syncthreads();
    #pragma unroll
    for (int i=ty;i<32;i+=8) wti[(size_t)(bc+i)*768 + br+tx] = f2b(tile[tx][i]);
  } else if (z < 12){  // Wo2 [3072][768] -> wto2 [768][3072]
    int bc = blockIdx.x*32, br = (blockIdx.y + (z-8)*24)*32;
    #pragma unroll
    for (int i=ty;i<32;i+=8) tile[i][tx] = Wo2[(size_t)(br+i)*768 + bc+tx];
    __syncthreads();
    #pragma unroll
    for (int i=ty;i<32;i+=8) wto2[(size_t)(bc+i)*3072 + br+tx] = f2b(tile[tx][i]);
  } else {             // castX (grid-stride float4) + bias concat
    int flat = (blockIdx.y*24 + blockIdx.x)*256 + ty*32 + tx;
    const int NF4 = ROWS*HID/4;
    for (int i=flat; i<NF4; i+=576*256){
      float4 f = ((const float4*)X)[i];
      union{ unsigned long long u; __bf16 h[4]; } pk;
      pk.h[0]=(__bf16)f.x; pk.h[1]=(__bf16)f.y; pk.h[2]=(__bf16)f.z; pk.h[3]=(__bf16)f.w;
      ((unsigned long long*)xb)[i] = pk.u;
    }
    if (flat < 768)       bqkv[flat] = bq[flat];
    else if (flat < 1536) bqkv[flat] = bk[flat-768];
    else if (flat < 2304) bqkv[flat] = bv[flat-1536];
  }
}

// V part of qkv [row][2304] -> Vt [z=(b,h)][d][s]
__global__ void vtrans(const bf16* __restrict__ v, bf16* __restrict__ vt)
{
  int z = blockIdx.z; int b = z/NHEAD, h = z - b*NHEAD;
  int d0 = blockIdx.x*32, s0 = blockIdx.y*32;
  __shared__ bf16 t[32][33];
  int tx = threadIdx.x, ty = threadIdx.y;
  #pragma unroll
  for (int i=ty;i<32;i+=8)
    t[i][tx] = v[(size_t)(b*SEQ + s0+i)*QKVW + h*HDIM + d0+tx];
  __syncthreads();
  #pragma unroll
  for (int i=ty;i<32;i+=8)
    vt[(size_t)z*HDIM*SEQ + (size_t)(d0+i)*SEQ + s0+tx] = t[tx][i];
}

// ---------------------------------------------------------------------------
// LayerNorm over 768 cols, one block per row. In-place-safe.
// ---------------------------------------------------------------------------
template<typename TO>
__global__ __launch_bounds__(256)
void ln768(const bf16* __restrict__ y, const float* __restrict__ g,
           const float* __restrict__ be, TO* __restrict__ dst)
{
  size_t row = blockIdx.x;
  const bf16* yr = y + row*HID;
  int t = threadIdx.x;
  float x0 = b2f(yr[t]), x1 = b2f(yr[t+256]), x2 = b2f(yr[t+512]);
  float s = x0+x1+x2, q = x0*x0+x1*x1+x2*x2;
  #pragma unroll
  for (int off=32; off; off>>=1){ s += __shfl_xor(s, off); q += __shfl_xor(q, off); }
  __shared__ float rs[4], rq[4];
  int wv = t>>6;
  if ((t&63)==0){ rs[wv]=s; rq[wv]=q; }
  __syncthreads();
  s = rs[0]+rs[1]+rs[2]+rs[3];
  q = rq[0]+rq[1]+rq[2]+rq[3];
  float mean = s*(1.0f/HID);
  float var  = q*(1.0f/HID) - mean*mean;
  float inv  = rsqrtf(var + 1e-12f);
  TO* dr = dst + row*HID;
  stf(dr, t,     (x0-mean)*inv*g[t    ] + be[t    ]);
  stf(dr, t+256, (x1-mean)*inv*g[t+256] + be[t+256]);
  stf(dr, t+512, (x2-mean)*inv*g[t+512] + be[t+512]);
}

// ---------------------------------------------------------------------------
// Dialog (CLS) block: 32 rows total
// ---------------------------------------------------------------------------
__global__ __launch_bounds__(256)
void cls_proj(const bf16* __restrict__ x2,
              const float* __restrict__ Wq, const float* __restrict__ bq,
              const float* __restrict__ Wk, const float* __restrict__ bk,
              const float* __restrict__ Wv, const float* __restrict__ bv,
              bf16* __restrict__ oq, bf16* __restrict__ ok, bf16* __restrict__ ov)
{
  int mat = blockIdx.x, row = blockIdx.y;
  const float* W  = mat==0 ? Wq : (mat==1 ? Wk : Wv);
  const float* bi = mat==0 ? bq : (mat==1 ? bk : bv);
  bf16* out       = mat==0 ? oq : (mat==1 ? ok : ov);
  __shared__ float a[HID];
  const bf16* xr = x2 + (size_t)row*SEQ*HID;
  for (int i=threadIdx.x;i<HID;i+=256) a[i] = b2f(xr[i]);
  __syncthreads();
  for (int c0=0;c0<HID;c0+=256){
    int col = c0 + threadIdx.x;
    float acc = 0.f;
    for (int k=0;k<HID;k++) acc += a[k]*W[(size_t)k*HID + col];
    out[(size_t)row*HID + col] = f2b(acc + bi[col]);
  }
}

__global__ __launch_bounds__(64)
void cls_attn(const bf16* __restrict__ q, const bf16* __restrict__ k,
              const bf16* __restrict__ v, bf16* __restrict__ ctx)
{
  int z = blockIdx.x; int bb = z/NHEAD, h = z - bb*NHEAD;
  __shared__ float P[8][8];
  int t = threadIdx.x;
  int qi = t>>3, ki = t&7;
  float s = 0.f;
  for (int d=0; d<HDIM; d++)
    s += b2f(q[(size_t)(bb*8+qi)*HID + h*HDIM + d]) *
         b2f(k[(size_t)(bb*8+ki)*HID + h*HDIM + d]);
  s = s*0.125f + (ki >= qi ? -10000.0f : 0.0f);
  float m = s;
  #pragma unroll
  for (int off=4; off; off>>=1) m = fmaxf(m, __shfl_xor(m, off, 8));
  float e = __expf(s - m);
  float sum = e;
  #pragma unroll
  for (int off=4; off; off>>=1) sum += __shfl_xor(sum, off, 8);
  P[qi][ki] = e/sum;
  __syncthreads();
  for (int q2=0; q2<8; q2++){
    float acc = 0.f;
    #pragma unroll
    for (int k2=0; k2<8; k2++)
      acc += P[q2][k2] * b2f(v[(size_t)(bb*8+k2)*HID + h*HDIM + t]);
    ctx[(size_t)(bb*8+q2)*HID + h*HDIM + t] = f2b(acc);
  }
}

__global__ __launch_bounds__(256)
void cls_out(const bf16* __restrict__ ctx, const float* __restrict__ Wo,
             const float* __restrict__ bo, const float* __restrict__ g,
             const float* __restrict__ be, bf16* __restrict__ x2)
{
  int row = blockIdx.x;
  __shared__ float a[HID];
  __shared__ float yrow[HID];
  const bf16* cr = ctx + (size_t)row*HID;
  bf16* xr = x2 + (size_t)row*SEQ*HID;
  for (int i=threadIdx.x;i<HID;i+=256) a[i] = b2f(cr[i]);
  __syncthreads();
  for (int c0=0;c0<HID;c0+=256){
    int col = c0 + threadIdx.x;
    float acc = 0.f;
    for (int k=0;k<HID;k++) acc += a[k]*Wo[(size_t)k*HID + col];
    yrow[col] = acc + bo[col] + b2f(xr[col]);
  }
  __syncthreads();
  int t = threadIdx.x;
  float x0 = yrow[t], x1 = yrow[t+256], x2v = yrow[t+512];
  float s = x0+x1+x2v, qq = x0*x0+x1*x1+x2v*x2v;
  #pragma unroll
  for (int off=32; off; off>>=1){ s += __shfl_xor(s, off); qq += __shfl_xor(qq, off); }
  __shared__ float rs[4], rq[4];
  int wv = t>>6;
  if ((t&63)==0){ rs[wv]=s; rq[wv]=qq; }
  __syncthreads();
  s = rs[0]+rs[1]+rs[2]+rs[3];
  qq = rq[0]+rq[1]+rq[2]+rq[3];
  float mean = s*(1.0f/HID);
  float var  = qq*(1.0f/HID) - mean*mean;
  float inv  = rsqrtf(var + 1e-12f);
  xr[t    ] = f2b((x0 -mean)*inv*g[t    ] + be[t    ]);
  xr[t+256] = f2b((x1 -mean)*inv*g[t+256] + be[t+256]);
  xr[t+512] = f2b((x2v-mean)*inv*g[t+512] + be[t+512]);
}

// ---------------------------------------------------------------------------
extern "C" void kernel_launch(void* const* d_in, const int* in_sizes, int n_in,
                              void* d_out, int out_size, void* d_ws, size_t ws_size,
                              hipStream_t stream)
{
  const float* X    = (const float*)d_in[0];
  const float* AM   = (const float*)d_in[1];
  const float* Wq   = (const float*)d_in[2];  const float* bq  = (const float*)d_in[3];
  const float* Wk   = (const float*)d_in[4];  const float* bk  = (const float*)d_in[5];
  const float* Wv   = (const float*)d_in[6];  const float* bv  = (const float*)d_in[7];
  const float* Wao  = (const float*)d_in[8];  const float* bao = (const float*)d_in[9];
  const float* ln1g = (const float*)d_in[10]; const float* ln1b= (const float*)d_in[11];
  const float* dWq  = (const float*)d_in[12]; const float* dbq = (const float*)d_in[13];
  const float* dWk  = (const float*)d_in[14]; const float* dbk = (const float*)d_in[15];
  const float* dWv  = (const float*)d_in[16]; const float* dbv = (const float*)d_in[17];
  const float* dWo  = (const float*)d_in[18]; const float* dbo = (const float*)d_in[19];
  const float* dlng = (const float*)d_in[20]; const float* dlnb= (const float*)d_in[21];
  const float* Wi   = (const float*)d_in[22]; const float* bi  = (const float*)d_in[23];
  const float* Wo2  = (const float*)d_in[24]; const float* bo2 = (const float*)d_in[25];
  const float* ln2g = (const float*)d_in[26]; const float* ln2b= (const float*)d_in[27];
  float* OUT = (float*)d_out;

  char* wp = (char*)d_ws;
  auto alloc = [&](size_t elems)->bf16*{
    bf16* p = (bf16*)wp;
    wp += ((elems*sizeof(bf16) + 255)/256)*256;
    return p;
  };
  bf16* wtq  = alloc(768*768);       // wtq..wtv contiguous => fused QKV B
  bf16* wtk  = alloc(768*768);
  bf16* wtv  = alloc(768*768);
  bf16* wtao = alloc(768*768);
  bf16* wti  = alloc((size_t)768*3072);
  bf16* wto2 = alloc((size_t)3072*768);
  float* bqkv = (float*)alloc(2304*2);
  bf16* qkv  = alloc((size_t)ROWS*QKVW);          // } qkv+vtb contiguous:
  bf16* vtb  = alloc((size_t)ROWS*HID);           // } inter aliases both
  bf16* inter = qkv;
  bf16* scb  = alloc((size_t)ROWS*HID);            // y/x2 slab
  bf16* yb   = scb;
  bf16* x2   = scb;
  bf16* ctxb = alloc((size_t)ROWS*HID);
  bf16* xb   = ctxb;   // bf16 X, dead before flash writes ctxb
  bf16* clsq = alloc(32*HID);
  bf16* clsk = alloc(32*HID);
  bf16* clsv = alloc(32*HID);
  bf16* clsc = alloc(32*HID);
  (void)wtk; (void)wtv;

  // one prep launch: 4x768^2 transposes + Wi/Wo2 transposes + castX + bias cat
  prep_all<<<dim3(24,24,13), dim3(32,8), 0, stream>>>(
      Wq, Wk, Wv, Wao, Wi, Wo2, X, bq, bk, bv, wtq, wti, wto2, xb, bqkv);

  // fused QKV projection: [16384,768] @ [768,2304] -> qkv[row][2304]
  gemm_bt<0,float><<<dim3(18,128),256,0,stream>>>(
      xb,768,  wtq,768,  qkv,QKVW,  768, bqkv, nullptr,0);

  vtrans<<<dim3(2,16,BATCH*NHEAD), dim3(32,8), 0, stream>>>(qkv + 1536, vtb);

  // fused flash attention -> ctxb
  flash_attn<<<dim3(NCHUNK, BATCH*NHEAD),256,0,stream>>>(qkv, vtb, AM, ctxb);

  // attn out-proj + bias + residual(X fp32) -> yb ; LN1 in place -> x2
  gemm_bt<2,float><<<dim3(6,128),256,0,stream>>>(
      ctxb,768,  wtao,768,  yb,768,  768, bao, X, 768);
  ln768<bf16><<<ROWS,256,0,stream>>>(yb, ln1g, ln1b, x2);

  // dialog (CLS) block on 32 rows
  cls_proj<<<dim3(3,32),256,0,stream>>>(x2, dWq,dbq, dWk,dbk, dWv,dbv,
                                        clsq, clsk, clsv);
  cls_attn<<<48,64,0,stream>>>(clsq, clsk, clsv, clsc);
  cls_out<<<32,256,0,stream>>>(clsc, dWo, dbo, dlng, dlnb, x2);

  // FFN1: inter = gelu(x2 @ Wi + bi)
  gemm_bt<1,float><<<dim3(24,128),256,0,stream>>>(
      x2,768,  wti,768,  inter,3072,  768, bi, nullptr,0);
  // FFN2: y = inter @ Wo2 + bo2 + x2
  gemm_bt<2,bf16><<<dim3(6,128),256,0,stream>>>(
      inter,3072,  wto2,3072,  yb,768,  3072, bo2, x2, 768);
  ln768<float><<<ROWS,256,0,stream>>>(yb, ln2g, ln2b, OUT);
}